// Round 10
// baseline (582.044 us; speedup 1.0000x reference)
//
#include <hip/hip_runtime.h>

#define N_NODES 100000
#define N_EDGES 600000
#define DIM 128
#define N_UNITS (N_NODES / 16)  // 6250 16-row units

typedef unsigned short ushortT;
typedef __attribute__((ext_vector_type(8))) short short8;
typedef __attribute__((ext_vector_type(4))) float float4v;
typedef __attribute__((ext_vector_type(4))) unsigned int uint4v;

__device__ __forceinline__ float bf2f(ushortT h) {
    return __builtin_bit_cast(float, ((unsigned int)h) << 16);
}
__device__ __forceinline__ float bflo(unsigned int p) {
    return __builtin_bit_cast(float, p << 16);
}
__device__ __forceinline__ float bfhi(unsigned int p) {
    return __builtin_bit_cast(float, p & 0xffff0000u);
}
__device__ __forceinline__ ushortT f2bf(float f) {  // RNE
    unsigned int x = __builtin_bit_cast(unsigned int, f);
    unsigned int r = (x + 0x7fffu + ((x >> 16) & 1u)) >> 16;
    return (ushortT)r;
}

// ---- prep: W (128x128 f32, KxN) -> transposed + XOR-swizzled bf16 hi/lo images
// element (k,n) stored at  n*128 + (((k>>3) ^ (n&15))<<3) + (k&7)
__global__ __launch_bounds__(256) void prep_kernel(const float* __restrict__ W1,
                                                   const float* __restrict__ W2,
                                                   ushortT* __restrict__ wt) {
    const float* Wf = (blockIdx.x == 0) ? W1 : W2;
    ushortT* outh = wt + blockIdx.x * 32768;
    ushortT* outl = outh + 16384;
    int t = threadIdx.x;
#pragma unroll
    for (int i = 0; i < 16; i++) {
        int c = t + i * 256;            // 0..4095
        int k = c >> 5;
        int n0 = (c & 31) * 4;
        float4v w = *(const float4v*)(Wf + k * 128 + n0);
        int g = k >> 3, kk = k & 7;
#pragma unroll
        for (int j = 0; j < 4; j++) {
            int n = n0 + j;
            ushortT wh = f2bf(w[j]);
            ushortT wl = f2bf(w[j] - bf2f(wh));
            int addr = n * 128 + ((g ^ (n & 15)) << 3) + kk;
            outh[addr] = wh;
            outl[addr] = wl;
        }
    }
}

// ---- x (f32) -> bf16 plane, once per call ----
__global__ __launch_bounds__(256) void xbf_kernel(const float* __restrict__ x,
                                                  ushortT* __restrict__ xb) {
    int i = blockIdx.x * 256 + threadIdx.x;  // 8-elem group; grid exact (6250)
    float4v a = ((const float4v*)x)[2 * i];
    float4v b = ((const float4v*)x)[2 * i + 1];
    ushortT o[8];
#pragma unroll
    for (int j = 0; j < 4; j++) o[j] = f2bf(a[j]);
#pragma unroll
    for (int j = 0; j < 4; j++) o[4 + j] = f2bf(b[j]);
    ((uint4v*)xb)[i] = *(const uint4v*)o;
}

// ---- CSR build ----
__global__ __launch_bounds__(256) void hist_kernel(const int* __restrict__ dst,
                                                   int* __restrict__ counts) {
    int e = blockIdx.x * 256 + threadIdx.x;
    if (e < N_EDGES) atomicAdd(&counts[dst[e]], 1);
}

#define SCAN_BLOCKS 98  // 98*1024 >= 100000

__global__ __launch_bounds__(1024) void blockscan_kernel(const int* __restrict__ counts,
                                                         int* __restrict__ local,
                                                         int* __restrict__ bsums) {
    __shared__ int wsum[16];
    int tid = threadIdx.x, lane = tid & 63, wid = tid >> 6;
    int i = blockIdx.x * 1024 + tid;
    int v = (i < N_NODES) ? counts[i] : 0;
    int incl = v;
#pragma unroll
    for (int off = 1; off < 64; off <<= 1) {
        int u = __shfl_up(incl, off);
        if (lane >= off) incl += u;
    }
    if (lane == 63) wsum[wid] = incl;
    __syncthreads();
    if (wid == 0) {
        int s = (lane < 16) ? wsum[lane] : 0;
#pragma unroll
        for (int off = 1; off < 16; off <<= 1) {
            int u = __shfl_up(s, off);
            if (lane >= off) s += u;
        }
        if (lane < 16) wsum[lane] = s;
    }
    __syncthreads();
    int excl = ((wid == 0) ? 0 : wsum[wid - 1]) + incl - v;
    if (i < N_NODES) local[i] = excl;
    if (tid == 0) bsums[blockIdx.x] = wsum[15];
}

__global__ __launch_bounds__(1024) void fixup_kernel(const int* __restrict__ local,
                                                     const int* __restrict__ bsums,
                                                     int* __restrict__ offsets,
                                                     int* __restrict__ cursor) {
    __shared__ int sbase;
    int tid = threadIdx.x;
    if (tid < 64) {
        int s = 0;
        for (int j = tid; j < blockIdx.x; j += 64) s += bsums[j];
#pragma unroll
        for (int off = 32; off >= 1; off >>= 1) s += __shfl_xor(s, off);
        if (tid == 0) sbase = s;
    }
    __syncthreads();
    int base = sbase;
    int i = blockIdx.x * 1024 + tid;
    if (i < N_NODES) {
        int o = local[i] + base;
        offsets[i] = o;
        cursor[i] = o;
    }
    if (blockIdx.x == 0 && tid == 0) offsets[N_NODES] = N_EDGES;
}

__global__ __launch_bounds__(256) void fill_kernel(const int* __restrict__ src,
                                                   const int* __restrict__ dst,
                                                   int* __restrict__ cursor,
                                                   int* __restrict__ eidx) {
    int e = blockIdx.x * 256 + threadIdx.x;
    if (e < N_EDGES) {
        int pos = atomicAdd(&cursor[dst[e]], 1);
        eidx[pos] = src[e];
    }
}

// lgkm-only wait: vmcnt=63, expcnt=7, lgkmcnt=0 (gfx9 encoding)
#define LGKM0() __builtin_amdgcn_s_waitcnt(0xC07F)

// ---- fused GIN layer: out = act(relu((h + sum_nbr h) @ W1 + b1) @ W2 + b2) ----
// Round-10: COALESCED group-gather. Round-9's gather was per-lane-divergent (64
// lanes -> ~16 random rows per VMEM op, ~64 cache lines; 8 loads in flight/lane)
// -> 0.8 TB/s. Now the wave splits into 4 groups of 16 lanes; each group gathers
// ONE node with lane-contiguous 16B slices (one 256B row per instruction = 4
// lines), 8 edge-rows in flight per group (4KB/wave nominal). CSR headers for the
// unit's 16 nodes are loaded once and distributed via __shfl. Each lane
// accumulates 8 dims in f32 (self first, then edges ascending == agg_kernel =>
// bit-identical), RNE hi/lo split, then routed to the MFMA fragment layout
// through the per-wave LDS slice ([4 nodes][128 dims] hi|lo, stride 136,
// lgkm-only waits, no barrier).
// Shell unchanged from round 9: 768 threads (12 waves), grid 256, 1 block/CU,
// all four W images resident (128KB), barrier-free persistent atomic unit-popper,
// GEMM1 -> in-LDS transpose -> GEMM2 -> scratch epilogue. LDS 158720B.
// OUT 1: bf16 plane (stride 128) + relu.  OUT 2: f32 (stride 128), no relu.
template <int OUT>
__global__ __launch_bounds__(768) void fused_kernel(const ushortT* __restrict__ Hprev,
                                                    const int* __restrict__ offs,
                                                    const int* __restrict__ eidx,
                                                    const ushortT* __restrict__ wtAll,
                                                    const float* __restrict__ b1,
                                                    const float* __restrict__ b2,
                                                    void* __restrict__ out,
                                                    int* __restrict__ ctr) {
    __shared__ ushortT SH[79360];  // 158720B: W images [0,65536), 12 x 1152-ushort wave slices

    int t = threadIdx.x, lane = t & 63, wid = t >> 6;  // wid 0..11
    int quad = lane >> 4, col16 = lane & 15;

    float bia1[8], bia2[8];
#pragma unroll
    for (int n = 0; n < 8; n++) {
        bia1[n] = b1[n * 16 + col16];
        bia2[n] = b2[n * 16 + col16];
    }

    // stage all four W images (128KB), once
    for (int i = t; i < 8192; i += 768)
        ((uint4v*)SH)[i] = ((const uint4v*)wtAll)[i];
    __syncthreads();  // the only block-wide barrier

    ushortT* scr = &SH[65536 + wid * 1152];  // 2304B per-wave slice

    for (;;) {
        int u = 0;
        if (lane == 0) u = atomicAdd(ctr, 1);
        u = __builtin_amdgcn_readfirstlane(u);
        if (u >= N_UNITS) break;
        int row0 = u * 16;

        // ---- coalesced 4-node-group gather -> A fragments via LDS slice ----
        // CSR headers for all 16 nodes of the unit, loaded once (lane&15 owns one)
        int begv = offs[row0 + col16];
        int cntv = offs[row0 + col16 + 1] - begv;
        short8 ah[4], al[4];
#pragma unroll
        for (int it = 0; it < 4; it++) {
            // gather roles: slotg = node slot (4 groups of 16 lanes), m = 16B slice
            int slotg = lane >> 4;
            int m = lane & 15;
            int node = row0 + it * 4 + slotg;
            int beg = __shfl(begv, it * 4 + slotg);
            int cnt = __shfl(cntv, it * 4 + slotg);
            const ushortT* hrow = Hprev + (size_t)node * DIM + m * 8;
            short8 selfv = *(const short8*)hrow;  // self row, coalesced 256B/group
            int nb = (cnt + 7) >> 3;              // 8-edge batches
            int idx[8];
            if (nb > 0) {
#pragma unroll
                for (int j = 0; j < 8; j++) {
                    int q = (j > cnt - 1) ? cnt - 1 : j;  // clamp: dups broadcast in L1
                    idx[j] = eidx[beg + q];
                }
            }
            float accf[8];
            uint4v su = __builtin_bit_cast(uint4v, selfv);
#pragma unroll
            for (int p = 0; p < 4; p++) {  // self first (same order as agg_kernel)
                accf[2 * p]     = bflo(su[p]);
                accf[2 * p + 1] = bfhi(su[p]);
            }
            for (int b = 0; b < nb; b++) {
                short8 rows[8];  // 8 x 256B rows in flight per group
#pragma unroll
                for (int j = 0; j < 8; j++)
                    rows[j] = *(const short8*)(Hprev + (size_t)idx[j] * DIM + m * 8);
                if (b + 1 < nb) {  // prefetch next batch indices under row latency
#pragma unroll
                    for (int j = 0; j < 8; j++) {
                        int q = (b + 1) * 8 + j;
                        if (q > cnt - 1) q = cnt - 1;
                        idx[j] = eidx[beg + q];
                    }
                }
                int rem = cnt - b * 8;
#pragma unroll
                for (int j = 0; j < 8; j++)
                    if (j < rem) {
                        uint4v uu = __builtin_bit_cast(uint4v, rows[j]);
#pragma unroll
                        for (int p = 0; p < 4; p++) {
                            accf[2 * p]     += bflo(uu[p]);
                            accf[2 * p + 1] += bfhi(uu[p]);
                        }
                    }
            }
            // RNE hi/lo split of the 8 owned dims (identical to old z planes)
            ushortT oh[8], ol[8];
#pragma unroll
            for (int e = 0; e < 8; e++) {
                ushortT hi = f2bf(accf[e]);
                oh[e] = hi;
                ol[e] = f2bf(accf[e] - bf2f(hi));
            }
            // route through the wave slice: [4 nodes][128 dims] hi | lo, stride 136
            LGKM0();  // WAR: previous it's fragment reads landed
            *(uint4v*)&scr[slotg * 136 + m * 8]       = *(const uint4v*)oh;
            *(uint4v*)&scr[544 + slotg * 136 + m * 8] = *(const uint4v*)ol;
            LGKM0();  // writes visible (per-wave slice, no barrier needed)
            // fragment roles: this it covers nodes c = it*4..it*4+3
            if ((col16 >> 2) == it) {
#pragma unroll
                for (int s = 0; s < 4; s++) {
                    ah[s] = *(const short8*)&scr[(col16 & 3) * 136 + quad * 8 + s * 32];
                    al[s] = *(const short8*)&scr[544 + (col16 & 3) * 136 + quad * 8 + s * 32];
                }
            }
        }

        // ---- GEMM1: acc = z @ W1 (3-term bf16 split; B loaded 8 frags at a time) ----
        float4v acc[8];
#pragma unroll
        for (int n = 0; n < 8; n++) acc[n] = (float4v)0.0f;
#pragma unroll
        for (int s = 0; s < 4; s++) {
            int sw = ((s * 4 + quad) ^ col16) << 3;
            short8 bh[8];
#pragma unroll
            for (int n = 0; n < 8; n++) bh[n] = *(const short8*)&SH[(n * 16 + col16) * 128 + sw];
            __builtin_amdgcn_s_setprio(1);
#pragma unroll
            for (int n = 0; n < 8; n++) {
                acc[n] = __builtin_amdgcn_mfma_f32_16x16x32_bf16(ah[s], bh[n], acc[n], 0, 0, 0);
                acc[n] = __builtin_amdgcn_mfma_f32_16x16x32_bf16(al[s], bh[n], acc[n], 0, 0, 0);
            }
            __builtin_amdgcn_s_setprio(0);
            short8 bl[8];
#pragma unroll
            for (int n = 0; n < 8; n++) bl[n] = *(const short8*)&SH[16384 + (n * 16 + col16) * 128 + sw];
            __builtin_amdgcn_s_setprio(1);
#pragma unroll
            for (int n = 0; n < 8; n++)
                acc[n] = __builtin_amdgcn_mfma_f32_16x16x32_bf16(ah[s], bl[n], acc[n], 0, 0, 0);
            __builtin_amdgcn_s_setprio(0);
        }

        // ---- transpose (per-wave scratch) + GEMM2 ----
        float4v acc2[8];
#pragma unroll
        for (int n = 0; n < 8; n++) acc2[n] = (float4v)0.0f;
#pragma unroll
        for (int s2 = 0; s2 < 4; s2++) {
            LGKM0();  // WAR: prior scratch reads landed before overwrite
#pragma unroll
            for (int h = 0; h < 2; h++) {
                int n = s2 * 2 + h;
#pragma unroll
                for (int i = 0; i < 4; i++) {
                    float vv = acc[n][i] + bia1[n];
                    vv = vv > 0.0f ? vv : 0.0f;
                    int row = quad * 4 + i;
                    ushortT hi = f2bf(vv);
                    ushortT lo = f2bf(vv - bf2f(hi));
                    int c8 = h * 2 + (col16 >> 3);
                    int base = row * 64 + (col16 & 7);
                    scr[base + ((c8 ^ (row & 7)) << 3)]       = hi;
                    scr[base + (((4 + c8) ^ (row & 7)) << 3)] = lo;
                }
            }
            LGKM0();  // writes visible before readback (per-wave scratch)
            short8 a2h = *(const short8*)&scr[col16 * 64 + ((quad ^ (col16 & 7)) << 3)];
            short8 a2l = *(const short8*)&scr[col16 * 64 + (((4 + quad) ^ (col16 & 7)) << 3)];
            int sw = ((s2 * 4 + quad) ^ col16) << 3;
            short8 bh[8];
#pragma unroll
            for (int n = 0; n < 8; n++) bh[n] = *(const short8*)&SH[32768 + (n * 16 + col16) * 128 + sw];
            __builtin_amdgcn_s_setprio(1);
#pragma unroll
            for (int n = 0; n < 8; n++) {
                acc2[n] = __builtin_amdgcn_mfma_f32_16x16x32_bf16(a2h, bh[n], acc2[n], 0, 0, 0);
                acc2[n] = __builtin_amdgcn_mfma_f32_16x16x32_bf16(a2l, bh[n], acc2[n], 0, 0, 0);
            }
            __builtin_amdgcn_s_setprio(0);
            short8 bl[8];
#pragma unroll
            for (int n = 0; n < 8; n++) bl[n] = *(const short8*)&SH[49152 + (n * 16 + col16) * 128 + sw];
            __builtin_amdgcn_s_setprio(1);
#pragma unroll
            for (int n = 0; n < 8; n++)
                acc2[n] = __builtin_amdgcn_mfma_f32_16x16x32_bf16(a2h, bl[n], acc2[n], 0, 0, 0);
            __builtin_amdgcn_s_setprio(0);
        }

        // ---- epilogue: 4-row passes through the wave slice, coalesced stores ----
        // C/D layout: col = n*16+col16, row = quad*4 + i
        LGKM0();  // GEMM2's last scratch reads done before epilogue overwrites
        if constexpr (OUT == 1) {
#pragma unroll
            for (int i = 0; i < 4; i++) {
#pragma unroll
                for (int n = 0; n < 8; n++) {
                    float vv = acc2[n][i] + bia2[n];
                    vv = vv > 0.0f ? vv : 0.0f;
                    scr[quad * 136 + n * 16 + col16] = f2bf(vv);
                }
                LGKM0();
                uint4v val = *(const uint4v*)&scr[(lane >> 4) * 136 + (lane & 15) * 8];
                *(uint4v*)((ushortT*)out +
                           (size_t)(row0 + (lane >> 4) * 4 + i) * 128 + (lane & 15) * 8) = val;
                LGKM0();  // WAR before next pass overwrites scratch
            }
        } else {
            float* trf = (float*)scr;  // 4 rows x 68 floats = 1088B <= slice
#pragma unroll
            for (int i = 0; i < 4; i++)
#pragma unroll
                for (int nh = 0; nh < 2; nh++) {
#pragma unroll
                    for (int k = 0; k < 4; k++) {
                        int n = nh * 4 + k;
                        trf[quad * 68 + k * 16 + col16] = acc2[n][i] + bia2[n];
                    }
                    LGKM0();
                    float4v val = *(const float4v*)&trf[(lane >> 4) * 68 + (lane & 15) * 4];
                    *(float4v*)((float*)out +
                                (size_t)(row0 + (lane >> 4) * 4 + i) * 128 +
                                nh * 64 + (lane & 15) * 4) = val;
                    LGKM0();
                }
        }
    }
}

extern "C" void kernel_launch(void* const* d_in, const int* in_sizes, int n_in,
                              void* d_out, int out_size, void* d_ws, size_t ws_size,
                              hipStream_t stream) {
    const float* x  = (const float*)d_in[0];
    const int* src  = (const int*)d_in[1];
    const int* dst  = (const int*)d_in[2];
    const float* W1 = (const float*)d_in[3];
    const float* b1 = (const float*)d_in[4];
    const float* W2 = (const float*)d_in[5];
    const float* b2 = (const float*)d_in[6];

    char* ws = (char*)d_ws;
    ushortT* wt     = (ushortT*)ws;                        // 128 KB: W1H|W1L|W2H|W2L (swizzled)
    int*     offs   = (int*)(ws + 131072);                 // 100001 ints
    int*     cursor = (int*)(ws + 531456);                 // 100000 ints
    int*     eidx   = (int*)(ws + 931456);                 // 600000 ints
    int*     local  = (int*)(ws + 3331456);                // 100000 ints
    int*     bsums  = (int*)(ws + 3731456);                // 98 ints (ends 3731848)
    int*     ctrs   = (int*)(ws + 3731848);                // 3 ints (unit pop counters)
    ushortT* xbf    = (ushortT*)(ws + 3731968);            // 25.6 MB bf16 x
    ushortT* h1     = (ushortT*)(ws + 3731968 + 25600000); // 25.6 MB bf16 h (layer0 out)
    ushortT* h2     = (ushortT*)(ws + 3731968 + 51200000); // 25.6 MB bf16 h (layer1 out)
    // total ~80.5 MB

    dim3 blk(256);
    const int gEdge = (N_EDGES + 255) / 256;    // 2344
    const int gXbf  = N_NODES * DIM / 8 / 256;  // 6250 exact
    const int gFus  = 256;                      // persistent: 1 block/CU, 12 waves

    prep_kernel<<<2, blk, 0, stream>>>(W1, W2, wt);
    xbf_kernel<<<gXbf, blk, 0, stream>>>(x, xbf);
    hipMemsetAsync(cursor, 0, N_NODES * sizeof(int), stream);
    hipMemsetAsync(ctrs, 0, 3 * sizeof(int), stream);
    hist_kernel<<<gEdge, blk, 0, stream>>>(dst, cursor);
    blockscan_kernel<<<SCAN_BLOCKS, 1024, 0, stream>>>(cursor, local, bsums);
    fixup_kernel<<<SCAN_BLOCKS, 1024, 0, stream>>>(local, bsums, offs, cursor);
    fill_kernel<<<gEdge, blk, 0, stream>>>(src, dst, cursor, eidx);

    // layer 0: gather from xbf, write h1
    fused_kernel<1><<<gFus, 768, 0, stream>>>(xbf, offs, eidx, wt, b1, b2, h1, ctrs + 0);
    // layer 1: gather from h1, write h2 (ping-pong: no gather/write race)
    fused_kernel<1><<<gFus, 768, 0, stream>>>(h1, offs, eidx, wt, b1, b2, h2, ctrs + 1);
    // layer 2: gather from h2, write f32 d_out (no relu)
    fused_kernel<2><<<gFus, 768, 0, stream>>>(h2, offs, eidx, wt, b1, b2, (float*)d_out, ctrs + 2);
}